// Round 1
// baseline (1926.522 us; speedup 1.0000x reference)
//
#include <hip/hip_runtime.h>
#include <math.h>

// MambaRecurrence: B=4, L=2048, D_MODEL=2048, D_STATE=16, DT_RANK=128
//
// Stage 1: x_dbl[M=8192,160] = hs[8192,2048] @ x_proj_w[160,2048]^T   (fp32 vector)
// Stage 2: delta[8192,2048]  = softplus(x_dbl[:, :128] @ dt_proj_w[2048,128]^T + b)
//          -> written into d_out (scan reads delta then overwrites same element with y)
// Stage 3: selective scan, 16 lanes per (b,d), shfl-xor(width=16) reduce for y_t.

#define DM   2048
#define DS   16
#define RNK  128
#define XDW  160   // RNK + 2*DS
#define LSEQ 2048
#define NB   4
#define MTOT (NB * LSEQ)   // 8192

// ---------------- GEMM1: x_dbl = hs @ W1^T ----------------
// grid 128, block 256. Tile: 64 rows x 160 cols. Thread (tm,tn)=(16,16):
// 4 consecutive rows, 10 consecutive cols. LDS-free: W1 (1.3MB) is L2/L1-hot,
// hs row chunks broadcast across tn lanes.
__global__ __launch_bounds__(256) void gemm1_xdbl(const float* __restrict__ hs,
                                                  const float* __restrict__ w1,
                                                  float* __restrict__ xdbl) {
    const int m0 = blockIdx.x * 64;
    const int tm = threadIdx.x >> 4;   // 0..15
    const int tn = threadIdx.x & 15;   // 0..15
    const int mb = m0 + tm * 4;
    const int nb = tn * 10;

    float acc[4][10];
    #pragma unroll
    for (int i = 0; i < 4; ++i)
        #pragma unroll
        for (int j = 0; j < 10; ++j) acc[i][j] = 0.f;

    const float* h0 = hs + (size_t)mb * DM;
    for (int k4 = 0; k4 < DM / 4; ++k4) {
        float4 a[4];
        #pragma unroll
        for (int i = 0; i < 4; ++i)
            a[i] = *(const float4*)(h0 + (size_t)i * DM + k4 * 4);
        #pragma unroll
        for (int j = 0; j < 10; ++j) {
            const float4 w = *(const float4*)(w1 + (size_t)(nb + j) * DM + k4 * 4);
            #pragma unroll
            for (int i = 0; i < 4; ++i)
                acc[i][j] += a[i].x * w.x + a[i].y * w.y + a[i].z * w.z + a[i].w * w.w;
        }
    }
    #pragma unroll
    for (int i = 0; i < 4; ++i)
        #pragma unroll
        for (int j = 0; j < 10; ++j)
            xdbl[(size_t)(mb + i) * XDW + nb + j] = acc[i][j];
}

// ---------------- GEMM2 + softplus: delta -> d_out ----------------
// grid (128,16), block 256. Tile 64 x 128. Thread: 4 rows x 8 consecutive cols.
__global__ __launch_bounds__(256) void gemm2_delta(const float* __restrict__ xdbl,
                                                   const float* __restrict__ w2,
                                                   const float* __restrict__ bias,
                                                   float* __restrict__ dout) {
    const int m0 = blockIdx.x * 64;
    const int n0 = blockIdx.y * 128;
    const int tm = threadIdx.x >> 4;
    const int tn = threadIdx.x & 15;
    const int mb = m0 + tm * 4;
    const int nb = n0 + tn * 8;

    float acc[4][8];
    #pragma unroll
    for (int i = 0; i < 4; ++i)
        #pragma unroll
        for (int j = 0; j < 8; ++j) acc[i][j] = 0.f;

    for (int k4 = 0; k4 < RNK / 4; ++k4) {
        float4 a[4];
        #pragma unroll
        for (int i = 0; i < 4; ++i)
            a[i] = *(const float4*)(xdbl + (size_t)(mb + i) * XDW + k4 * 4);
        #pragma unroll
        for (int j = 0; j < 8; ++j) {
            const float4 w = *(const float4*)(w2 + (size_t)(nb + j) * RNK + k4 * 4);
            #pragma unroll
            for (int i = 0; i < 4; ++i)
                acc[i][j] += a[i].x * w.x + a[i].y * w.y + a[i].z * w.z + a[i].w * w.w;
        }
    }

    #pragma unroll
    for (int i = 0; i < 4; ++i) {
        float r[8];
        #pragma unroll
        for (int j = 0; j < 8; ++j) {
            const float x = acc[i][j] + bias[nb + j];
            // stable softplus: log1p(exp(x)), linear for large x
            r[j] = (x > 20.f) ? x : log1pf(expf(x));
        }
        float* o = dout + (size_t)(mb + i) * DM + nb;
        *(float4*)(o)     = make_float4(r[0], r[1], r[2], r[3]);
        *(float4*)(o + 4) = make_float4(r[4], r[5], r[6], r[7]);
    }
}

// ---------------- Selective scan ----------------
// grid (DM/16=128, NB=4), block 256 = 16 groups of 16 lanes. Group g handles
// (b, d = bx*16+g); lane n owns state h[n]. Reads delta from d_out, overwrites
// the same element with y (exclusive per group, read-before-write in lockstep).
__global__ __launch_bounds__(256) void scan_kernel(const float* __restrict__ hs,
                                                   const float* __restrict__ xdbl,
                                                   const float* __restrict__ Alog,
                                                   const float* __restrict__ Dvec,
                                                   float* __restrict__ dout) {
    const int b = blockIdx.y;
    const int g = threadIdx.x >> 4;   // 0..15
    const int n = threadIdx.x & 15;   // 0..15
    const int d = blockIdx.x * 16 + g;

    const float A  = -expf(Alog[(size_t)d * DS + n]);
    const float Dd = Dvec[d];

    float h = 0.f;
    const size_t base = (size_t)b * LSEQ;
    for (int t = 0; t < LSEQ; ++t) {
        const size_t row = base + t;
        const float delta = dout[row * DM + d];
        const float u     = hs[row * DM + d];
        const float Bv    = xdbl[row * XDW + RNK + n];
        const float Cv    = xdbl[row * XDW + RNK + DS + n];

        h = __expf(delta * A) * h + (delta * u) * Bv;

        float p = h * Cv;
        p += __shfl_xor(p, 1, 16);
        p += __shfl_xor(p, 2, 16);
        p += __shfl_xor(p, 4, 16);
        p += __shfl_xor(p, 8, 16);

        if (n == 0) dout[row * DM + d] = p + u * Dd;
    }
}

extern "C" void kernel_launch(void* const* d_in, const int* in_sizes, int n_in,
                              void* d_out, int out_size, void* d_ws, size_t ws_size,
                              hipStream_t stream) {
    const float* hs   = (const float*)d_in[0];  // (4,2048,2048)
    const float* w1   = (const float*)d_in[1];  // (160,2048)
    const float* w2   = (const float*)d_in[2];  // (2048,128)
    const float* bias = (const float*)d_in[3];  // (2048,)
    const float* Alog = (const float*)d_in[4];  // (2048,16)
    const float* Dvec = (const float*)d_in[5];  // (2048,)
    float* dout = (float*)d_out;                // (4,2048,2048)
    float* xdbl = (float*)d_ws;                 // 8192*160 floats = 5.24 MB

    hipLaunchKernelGGL(gemm1_xdbl,  dim3(MTOT / 64),             dim3(256), 0, stream, hs, w1, xdbl);
    hipLaunchKernelGGL(gemm2_delta, dim3(MTOT / 64, DM / 128),   dim3(256), 0, stream, xdbl, w2, bias, dout);
    hipLaunchKernelGGL(scan_kernel, dim3(DM / 16, NB),           dim3(256), 0, stream, hs, xdbl, Alog, Dvec, dout);
}

// Round 2
// 1558.541 us; speedup vs baseline: 1.2361x; 1.2361x over previous
//
#include <hip/hip_runtime.h>
#include <math.h>

// MambaRecurrence: B=4, L=2048, D_MODEL=2048, D_STATE=16, DT_RANK=128
//
// Stage 1: x_dbl[M=8192,160] = hs[8192,2048] @ x_proj_w[160,2048]^T   (fp32 vector)
// Stage 2: delta[8192,2048]  = softplus(x_dbl[:, :128] @ dt_proj_w[2048,128]^T + b)
//          -> written into d_out (scan reads delta then overwrites same element with y)
// Stage 3: selective scan, 16 lanes per (b,d), depth-4 register prefetch pipeline.

#define DM   2048
#define DS   16
#define RNK  128
#define XDW  160   // RNK + 2*DS
#define LSEQ 2048
#define NB   4
#define MTOT (NB * LSEQ)   // 8192

// ---------------- GEMM1: x_dbl = hs @ W1^T ----------------
// grid 512 (16 rows/block), block 256. Thread: 2 rows x 5 cols.
// 2048 waves = 8/CU = 2/SIMD. Per k4-step: 7 float4 loads, 40 FMA.
__global__ __launch_bounds__(256) void gemm1_xdbl(const float* __restrict__ hs,
                                                  const float* __restrict__ w1,
                                                  float* __restrict__ xdbl) {
    const int m0 = blockIdx.x * 16;
    const int tm = threadIdx.x >> 5;   // 0..7  -> rows 2tm, 2tm+1
    const int tn = threadIdx.x & 31;   // 0..31 -> cols tn*5 .. tn*5+4
    const int r0 = m0 + tm * 2;
    const int nb = tn * 5;

    float acc[2][5];
    #pragma unroll
    for (int i = 0; i < 2; ++i)
        #pragma unroll
        for (int j = 0; j < 5; ++j) acc[i][j] = 0.f;

    const float* h0 = hs + (size_t)r0 * DM;
    #pragma unroll 2
    for (int k4 = 0; k4 < DM / 4; ++k4) {
        const float4 a0 = *(const float4*)(h0 + k4 * 4);
        const float4 a1 = *(const float4*)(h0 + DM + k4 * 4);
        #pragma unroll
        for (int j = 0; j < 5; ++j) {
            const float4 w = *(const float4*)(w1 + (size_t)(nb + j) * DM + k4 * 4);
            acc[0][j] += a0.x * w.x + a0.y * w.y + a0.z * w.z + a0.w * w.w;
            acc[1][j] += a1.x * w.x + a1.y * w.y + a1.z * w.z + a1.w * w.w;
        }
    }
    #pragma unroll
    for (int i = 0; i < 2; ++i)
        #pragma unroll
        for (int j = 0; j < 5; ++j)
            xdbl[(size_t)(r0 + i) * XDW + nb + j] = acc[i][j];
}

// ---------------- GEMM2 + softplus: delta -> d_out ----------------
// grid (128,16), block 256. Tile 64 x 128. Thread: 4 rows x 8 consecutive cols.
__global__ __launch_bounds__(256) void gemm2_delta(const float* __restrict__ xdbl,
                                                   const float* __restrict__ w2,
                                                   const float* __restrict__ bias,
                                                   float* __restrict__ dout) {
    const int m0 = blockIdx.x * 64;
    const int n0 = blockIdx.y * 128;
    const int tm = threadIdx.x >> 4;
    const int tn = threadIdx.x & 15;
    const int mb = m0 + tm * 4;
    const int nb = n0 + tn * 8;

    float acc[4][8];
    #pragma unroll
    for (int i = 0; i < 4; ++i)
        #pragma unroll
        for (int j = 0; j < 8; ++j) acc[i][j] = 0.f;

    for (int k4 = 0; k4 < RNK / 4; ++k4) {
        float4 a[4];
        #pragma unroll
        for (int i = 0; i < 4; ++i)
            a[i] = *(const float4*)(xdbl + (size_t)(mb + i) * XDW + k4 * 4);
        #pragma unroll
        for (int j = 0; j < 8; ++j) {
            const float4 w = *(const float4*)(w2 + (size_t)(nb + j) * RNK + k4 * 4);
            #pragma unroll
            for (int i = 0; i < 4; ++i)
                acc[i][j] += a[i].x * w.x + a[i].y * w.y + a[i].z * w.z + a[i].w * w.w;
        }
    }

    #pragma unroll
    for (int i = 0; i < 4; ++i) {
        float r[8];
        #pragma unroll
        for (int j = 0; j < 8; ++j) {
            const float x = acc[i][j] + bias[nb + j];
            r[j] = (x > 20.f) ? x : log1pf(expf(x));
        }
        float* o = dout + (size_t)(mb + i) * DM + nb;
        *(float4*)(o)     = make_float4(r[0], r[1], r[2], r[3]);
        *(float4*)(o + 4) = make_float4(r[4], r[5], r[6], r[7]);
    }
}

// ---------------- Selective scan ----------------
// grid (DM/16=128, NB=4), block 256 = 16 groups of 16 lanes. Group g handles
// (b, d = bx*16+g); lane n owns state h[n].
// delta_in and y_out are BOTH d_out: restrict is sound because every
// same-address (load,store) pair is dataflow-dependent within its owning
// group (delta[b,t,d] is consumed to produce y[b,t,d]); all cross-iteration
// reorderings touch distinct addresses. This unblocks prefetching.
// Depth-4 register pipeline; #pragma unroll 4 keeps slot indices static
// (runtime-indexed arrays would spill to scratch).
__global__ __launch_bounds__(256) void scan_kernel(const float* __restrict__ hs,
                                                   const float* __restrict__ xdbl,
                                                   const float* __restrict__ Alog,
                                                   const float* __restrict__ Dvec,
                                                   const float* __restrict__ delta_in,
                                                   float* __restrict__ y_out) {
    const int b = blockIdx.y;
    const int g = threadIdx.x >> 4;   // 0..15
    const int n = threadIdx.x & 15;   // 0..15
    const int d = blockIdx.x * 16 + g;

    const float A  = -expf(Alog[(size_t)d * DS + n]);
    const float Dd = Dvec[d];

    const size_t base = (size_t)b * LSEQ;

    float pd[4], pu[4], pB[4], pC[4];
    #pragma unroll
    for (int j = 0; j < 4; ++j) {
        const size_t row = base + j;
        pd[j] = delta_in[row * DM + d];
        pu[j] = hs[row * DM + d];
        pB[j] = xdbl[row * XDW + RNK + n];
        pC[j] = xdbl[row * XDW + RNK + DS + n];
    }

    float h = 0.f;
    #pragma unroll 4
    for (int t = 0; t < LSEQ; ++t) {
        const int j = t & 3;
        const float delta = pd[j];
        const float u     = pu[j];
        const float Bv    = pB[j];
        const float Cv    = pC[j];

        // issue prefetch for t+4 into the just-freed slot (clamped; the
        // clamped loads near the end are never consumed)
        const int tp = (t + 4 < LSEQ) ? (t + 4) : (LSEQ - 1);
        const size_t prow = base + tp;
        pd[j] = delta_in[prow * DM + d];
        pu[j] = hs[prow * DM + d];
        pB[j] = xdbl[prow * XDW + RNK + n];
        pC[j] = xdbl[prow * XDW + RNK + DS + n];

        h = __expf(delta * A) * h + (delta * u) * Bv;

        float p = h * Cv;
        p += __shfl_xor(p, 1, 16);
        p += __shfl_xor(p, 2, 16);
        p += __shfl_xor(p, 4, 16);
        p += __shfl_xor(p, 8, 16);

        if (n == 0) y_out[(base + t) * DM + d] = p + u * Dd;
    }
}

extern "C" void kernel_launch(void* const* d_in, const int* in_sizes, int n_in,
                              void* d_out, int out_size, void* d_ws, size_t ws_size,
                              hipStream_t stream) {
    const float* hs   = (const float*)d_in[0];  // (4,2048,2048)
    const float* w1   = (const float*)d_in[1];  // (160,2048)
    const float* w2   = (const float*)d_in[2];  // (2048,128)
    const float* bias = (const float*)d_in[3];  // (2048,)
    const float* Alog = (const float*)d_in[4];  // (2048,16)
    const float* Dvec = (const float*)d_in[5];  // (2048,)
    float* dout = (float*)d_out;                // (4,2048,2048)
    float* xdbl = (float*)d_ws;                 // 8192*160 floats = 5.24 MB

    hipLaunchKernelGGL(gemm1_xdbl,  dim3(MTOT / 16),           dim3(256), 0, stream, hs, w1, xdbl);
    hipLaunchKernelGGL(gemm2_delta, dim3(MTOT / 64, DM / 128), dim3(256), 0, stream, xdbl, w2, bias, dout);
    hipLaunchKernelGGL(scan_kernel, dim3(DM / 16, NB),         dim3(256), 0, stream,
                       hs, xdbl, Alog, Dvec, dout, dout);
}

// Round 4
// 615.448 us; speedup vs baseline: 3.1303x; 2.5324x over previous
//
#include <hip/hip_runtime.h>
#include <math.h>

// MambaRecurrence: B=4, L=2048, D_MODEL=2048, D_STATE=16, DT_RANK=128
// Stage 1: x_dbl[8192,160] = hs[8192,2048] @ x_proj_w[160,2048]^T  (LDS-tiled fp32, K-split)
// Stage 2: delta[8192,2048] = softplus(x_dbl[:, :128] @ dt_proj_w[2048,128]^T + b)  (LDS-tiled)
// Stage 3: selective scan, depth-8 prefetch, batched-8 shfl reduction.
//
// (Round 3 resubmission: round-2 bench was lost to GPUAcquisitionTimeout.)

#define DM   2048
#define DS   16
#define RNK  128
#define XDW  160   // RNK + 2*DS
#define LSEQ 2048
#define NB   4
#define MTOT (NB * LSEQ)   // 8192

// ================= GEMM1: x_dbl = hs @ W1^T =================
#define G1_BM   128
#define G1_BK   32
#define G1_KS   8                  // K-split factor
#define G1_KPB  (DM / G1_KS)       // 256 K per block
#define G1_NCH  (G1_KPB / G1_BK)   // 8 chunks
#define XDBL_ELEMS ((size_t)MTOT * XDW)

// ATOMIC=true: accumulate into pre-zeroed xdbl via atomicAdd.
// ATOMIC=false: write partials to out[ks][8192][160]; reduced by reduce_part.
template<bool ATOMIC>
__global__ __launch_bounds__(256) void gemm1_kern(const float* __restrict__ hs,
                                                  const float* __restrict__ w1,
                                                  float* __restrict__ out) {
    __shared__ float aT[G1_BK][G1_BM + 4];   // [k][m], k-major
    __shared__ float bT[G1_BK][160 + 4];     // [k][n]
    const int m0 = blockIdx.x * G1_BM;
    const int k0 = blockIdx.y * G1_KPB;
    const int tid = threadIdx.x;
    const int tm = tid >> 4, tn = tid & 15;
    const int r0 = tm * 8;                   // 8 rows per thread
    const int sk = (tid & 7) * 4;            // staging: k-offset 0..28
    const int sr = tid >> 3;                 // staging: row 0..31

    float acc[8][10];
    #pragma unroll
    for (int i = 0; i < 8; ++i)
        #pragma unroll
        for (int j = 0; j < 10; ++j) acc[i][j] = 0.f;

    for (int ch = 0; ch < G1_NCH; ++ch) {
        const int kc = k0 + ch * G1_BK;
        __syncthreads();
        #pragma unroll
        for (int p = 0; p < 4; ++p) {       // hs tile 128x32, coalesced, transpose into LDS
            const int row = sr + p * 32;
            const float4 v = *(const float4*)(hs + (size_t)(m0 + row) * DM + kc + sk);
            aT[sk + 0][row] = v.x; aT[sk + 1][row] = v.y;
            aT[sk + 2][row] = v.z; aT[sk + 3][row] = v.w;
        }
        #pragma unroll
        for (int p = 0; p < 5; ++p) {       // w1 tile 160x32
            const int row = sr + p * 32;
            const float4 v = *(const float4*)(w1 + (size_t)row * DM + kc + sk);
            bT[sk + 0][row] = v.x; bT[sk + 1][row] = v.y;
            bT[sk + 2][row] = v.z; bT[sk + 3][row] = v.w;
        }
        __syncthreads();
        #pragma unroll 4
        for (int k = 0; k < G1_BK; ++k) {
            const float4 a0 = *(const float4*)&aT[k][r0];
            const float4 a1 = *(const float4*)&aT[k][r0 + 4];
            const float4 b0 = *(const float4*)&bT[k][tn * 4];
            const float4 b1 = *(const float4*)&bT[k][64 + tn * 4];
            const float2 b2 = *(const float2*)&bT[k][128 + tn * 2];
            const float av[8]  = {a0.x,a0.y,a0.z,a0.w,a1.x,a1.y,a1.z,a1.w};
            const float bv[10] = {b0.x,b0.y,b0.z,b0.w,b1.x,b1.y,b1.z,b1.w,b2.x,b2.y};
            #pragma unroll
            for (int i = 0; i < 8; ++i)
                #pragma unroll
                for (int j = 0; j < 10; ++j)
                    acc[i][j] += av[i] * bv[j];
        }
    }
    #pragma unroll
    for (int i = 0; i < 8; ++i) {
        const size_t rowoff = (size_t)(m0 + r0 + i) * XDW;
        #pragma unroll
        for (int j = 0; j < 10; ++j) {
            const int col = (j < 4) ? (tn * 4 + j)
                          : (j < 8) ? (64 + tn * 4 + (j - 4))
                                    : (128 + tn * 2 + (j - 8));
            if (ATOMIC) atomicAdd(&out[rowoff + col], acc[i][j]);
            else        out[(size_t)blockIdx.y * XDBL_ELEMS + rowoff + col] = acc[i][j];
        }
    }
}

__global__ __launch_bounds__(256) void zero_xdbl(float4* p) {
    p[blockIdx.x * 256 + threadIdx.x] = make_float4(0.f, 0.f, 0.f, 0.f);  // 327680 float4s
}

__global__ __launch_bounds__(256) void reduce_part(const float* __restrict__ part,
                                                   float* __restrict__ xdbl) {
    const size_t i = (size_t)blockIdx.x * 256 + threadIdx.x;   // over 1,310,720
    float s = 0.f;
    #pragma unroll
    for (int k = 0; k < G1_KS; ++k) s += part[(size_t)k * XDBL_ELEMS + i];
    xdbl[i] = s;
}

// ================= GEMM2 + softplus =================
#define G2_BM 128
#define G2_BN 128
#define G2_BK 32
__global__ __launch_bounds__(256) void gemm2_delta(const float* __restrict__ xdbl,
                                                   const float* __restrict__ w2,
                                                   const float* __restrict__ bias,
                                                   float* __restrict__ dout) {
    __shared__ float xT[G2_BK][G2_BM + 4];
    __shared__ float wT[G2_BK][G2_BN + 4];
    const int m0 = blockIdx.x * G2_BM;
    const int n0 = blockIdx.y * G2_BN;
    const int tid = threadIdx.x;
    const int tm = tid >> 4, tn = tid & 15;
    const int r0 = tm * 8;
    const int sk = (tid & 7) * 4;
    const int sr = tid >> 3;

    float acc[8][8];
    #pragma unroll
    for (int i = 0; i < 8; ++i)
        #pragma unroll
        for (int j = 0; j < 8; ++j) acc[i][j] = 0.f;

    for (int ch = 0; ch < RNK / G2_BK; ++ch) {
        const int kc = ch * G2_BK;
        __syncthreads();
        #pragma unroll
        for (int p = 0; p < 4; ++p) {
            const int row = sr + p * 32;
            const float4 v = *(const float4*)(xdbl + (size_t)(m0 + row) * XDW + kc + sk);
            xT[sk + 0][row] = v.x; xT[sk + 1][row] = v.y;
            xT[sk + 2][row] = v.z; xT[sk + 3][row] = v.w;
        }
        #pragma unroll
        for (int p = 0; p < 4; ++p) {
            const int row = sr + p * 32;
            const float4 v = *(const float4*)(w2 + (size_t)(n0 + row) * RNK + kc + sk);
            wT[sk + 0][row] = v.x; wT[sk + 1][row] = v.y;
            wT[sk + 2][row] = v.z; wT[sk + 3][row] = v.w;
        }
        __syncthreads();
        #pragma unroll 4
        for (int k = 0; k < G2_BK; ++k) {
            const float4 a0 = *(const float4*)&xT[k][r0];
            const float4 a1 = *(const float4*)&xT[k][r0 + 4];
            const float4 b0 = *(const float4*)&wT[k][tn * 4];
            const float4 b1 = *(const float4*)&wT[k][64 + tn * 4];
            const float av[8] = {a0.x,a0.y,a0.z,a0.w,a1.x,a1.y,a1.z,a1.w};
            const float bv[8] = {b0.x,b0.y,b0.z,b0.w,b1.x,b1.y,b1.z,b1.w};
            #pragma unroll
            for (int i = 0; i < 8; ++i)
                #pragma unroll
                for (int j = 0; j < 8; ++j)
                    acc[i][j] += av[i] * bv[j];
        }
    }
    #pragma unroll
    for (int i = 0; i < 8; ++i) {
        float r[8];
        #pragma unroll
        for (int j = 0; j < 8; ++j) {
            const int col = (j < 4) ? (tn * 4 + j) : (64 + tn * 4 + (j - 4));
            const float x = acc[i][j] + bias[n0 + col];
            r[j] = (x > 20.f) ? x : log1pf(expf(x));
        }
        float* o = dout + (size_t)(m0 + r0 + i) * DM + n0;
        *(float4*)(o + tn * 4)      = make_float4(r[0], r[1], r[2], r[3]);
        *(float4*)(o + 64 + tn * 4) = make_float4(r[4], r[5], r[6], r[7]);
    }
}

// ================= Selective scan =================
// 16 lanes per (b,d); lane n owns h[n]. Depth-8 register prefetch.
// y-reduction batched every 8 t: 8 independent shfl-xor trees (ds-pipe ILP),
// store by 8 lanes (static cndmask select chain; no runtime-indexed arrays).
// delta_in/y_out both alias d_out; every same-address load/store pair is
// dataflow-dependent within its owning group, so restrict is sound.
__global__ __launch_bounds__(256) void scan_kernel(const float* __restrict__ hs,
                                                   const float* __restrict__ xdbl,
                                                   const float* __restrict__ Alog,
                                                   const float* __restrict__ Dvec,
                                                   const float* __restrict__ delta_in,
                                                   float* __restrict__ y_out) {
    const int b = blockIdx.y;
    const int g = threadIdx.x >> 4;
    const int n = threadIdx.x & 15;
    const int d = blockIdx.x * 16 + g;

    const float A  = -expf(Alog[(size_t)d * DS + n]);
    const float Dd = Dvec[d];
    const size_t base = (size_t)b * LSEQ;

    float pd[8], pu[8], pB[8], pC[8];
    #pragma unroll
    for (int j = 0; j < 8; ++j) {
        const size_t row = base + j;
        pd[j] = delta_in[row * DM + d];
        pu[j] = hs[row * DM + d];
        pB[j] = xdbl[row * XDW + RNK + n];
        pC[j] = xdbl[row * XDW + RNK + DS + n];
    }

    float h = 0.f;
    for (int t0 = 0; t0 < LSEQ; t0 += 8) {
        float pp[8], uD[8];
        #pragma unroll
        for (int j = 0; j < 8; ++j) {
            const float delta = pd[j];
            const float u     = pu[j];
            const float Bv    = pB[j];
            const float Cv    = pC[j];
            uD[j] = u * Dd;
            // prefetch t0+j+8 into the freed slot (clamped; junk never consumed)
            const int tp = (t0 + j + 8 < LSEQ) ? (t0 + j + 8) : (LSEQ - 1);
            const size_t prow = base + tp;
            pd[j] = delta_in[prow * DM + d];
            pu[j] = hs[prow * DM + d];
            pB[j] = xdbl[prow * XDW + RNK + n];
            pC[j] = xdbl[prow * XDW + RNK + DS + n];

            h = __expf(delta * A) * h + (delta * u) * Bv;
            pp[j] = h * Cv;
        }
        #pragma unroll
        for (int s = 1; s < 16; s <<= 1)
            #pragma unroll
            for (int j = 0; j < 8; ++j)
                pp[j] += __shfl_xor(pp[j], s, 16);
        float yv[8];
        #pragma unroll
        for (int j = 0; j < 8; ++j) yv[j] = pp[j] + uD[j];
        float v = yv[0];
        #pragma unroll
        for (int j = 1; j < 8; ++j) v = (n == j) ? yv[j] : v;
        if (n < 8) y_out[(base + t0 + n) * DM + d] = v;
    }
}

extern "C" void kernel_launch(void* const* d_in, const int* in_sizes, int n_in,
                              void* d_out, int out_size, void* d_ws, size_t ws_size,
                              hipStream_t stream) {
    const float* hs   = (const float*)d_in[0];
    const float* w1   = (const float*)d_in[1];
    const float* w2   = (const float*)d_in[2];
    const float* bias = (const float*)d_in[3];
    const float* Alog = (const float*)d_in[4];
    const float* Dvec = (const float*)d_in[5];
    float* dout = (float*)d_out;
    float* xdbl = (float*)d_ws;                          // 5.24 MB

    const size_t PART_OFF = (size_t)8 << 20;             // partials at ws+8MB
    const size_t need = PART_OFF + (size_t)G1_KS * XDBL_ELEMS * sizeof(float);

    if (ws_size >= need) {
        float* part = (float*)((char*)d_ws + PART_OFF);
        hipLaunchKernelGGL((gemm1_kern<false>), dim3(MTOT / G1_BM, G1_KS), dim3(256), 0, stream, hs, w1, part);
        hipLaunchKernelGGL(reduce_part, dim3((unsigned)(XDBL_ELEMS / 256)), dim3(256), 0, stream, part, xdbl);
    } else {
        hipLaunchKernelGGL(zero_xdbl, dim3((unsigned)(XDBL_ELEMS / 1024)), dim3(256), 0, stream, (float4*)xdbl);
        hipLaunchKernelGGL((gemm1_kern<true>), dim3(MTOT / G1_BM, G1_KS), dim3(256), 0, stream, hs, w1, xdbl);
    }
    hipLaunchKernelGGL(gemm2_delta, dim3(MTOT / G2_BM, DM / G2_BN), dim3(256), 0, stream, xdbl, w2, bias, dout);
    hipLaunchKernelGGL(scan_kernel, dim3(DM / 16, NB), dim3(256), 0, stream,
                       hs, xdbl, Alog, Dvec, dout, dout);
}

// Round 5
// 577.305 us; speedup vs baseline: 3.3371x; 1.0661x over previous
//
#include <hip/hip_runtime.h>
#include <math.h>

// MambaRecurrence: B=4, L=2048, D_MODEL=2048, D_STATE=16, DT_RANK=128
// Stage 1: x_dbl[8192,160] = hs[8192,2048] @ x_proj_w[160,2048]^T  (LDS fp32, BM=64, K-split 8)
// Stage 2: delta[8192,2048] = softplus(x_dbl[:, :128] @ dt_proj_w[2048,128]^T + b)
// Stage 3: scan — depth-8 prefetch, uint32 strength-reduced addressing, peeled tail.

#define DM   2048
#define DS   16
#define RNK  128
#define XDW  160   // RNK + 2*DS
#define LSEQ 2048
#define NB   4
#define MTOT (NB * LSEQ)   // 8192

// ================= GEMM1: x_dbl = hs @ W1^T =================
#define G1_BM   64
#define G1_BK   32
#define G1_KS   8                  // K-split factor
#define G1_KPB  (DM / G1_KS)       // 256 K per block
#define G1_NCH  (G1_KPB / G1_BK)   // 8 chunks
#define XDBL_ELEMS ((size_t)MTOT * XDW)

// ATOMIC=true: accumulate into pre-zeroed xdbl via atomicAdd.
// ATOMIC=false: write partials to out[ks][8192][160]; reduced by reduce_part.
template<bool ATOMIC>
__global__ __launch_bounds__(256) void gemm1_kern(const float* __restrict__ hs,
                                                  const float* __restrict__ w1,
                                                  float* __restrict__ out) {
    __shared__ float aT[G1_BK][G1_BM + 4];   // [k][m]
    __shared__ float bT[G1_BK][160 + 4];     // [k][n]
    const int m0 = blockIdx.x * G1_BM;
    const int k0 = blockIdx.y * G1_KPB;
    const int tid = threadIdx.x;
    const int tm = tid >> 4, tn = tid & 15;
    const int r0 = tm * 4;                   // 4 rows per thread
    const int sk = (tid & 7) * 4;            // staging k-offset 0..28
    const int sr = tid >> 3;                 // staging row 0..31

    float acc[4][10];
    #pragma unroll
    for (int i = 0; i < 4; ++i)
        #pragma unroll
        for (int j = 0; j < 10; ++j) acc[i][j] = 0.f;

    for (int ch = 0; ch < G1_NCH; ++ch) {
        const int kc = k0 + ch * G1_BK;
        __syncthreads();
        #pragma unroll
        for (int p = 0; p < 2; ++p) {        // hs tile 64x32
            const int row = sr + p * 32;
            const float4 v = *(const float4*)(hs + (size_t)(m0 + row) * DM + kc + sk);
            aT[sk + 0][row] = v.x; aT[sk + 1][row] = v.y;
            aT[sk + 2][row] = v.z; aT[sk + 3][row] = v.w;
        }
        #pragma unroll
        for (int p = 0; p < 5; ++p) {        // w1 tile 160x32
            const int row = sr + p * 32;
            const float4 v = *(const float4*)(w1 + (size_t)row * DM + kc + sk);
            bT[sk + 0][row] = v.x; bT[sk + 1][row] = v.y;
            bT[sk + 2][row] = v.z; bT[sk + 3][row] = v.w;
        }
        __syncthreads();
        #pragma unroll 4
        for (int k = 0; k < G1_BK; ++k) {
            const float4 a0 = *(const float4*)&aT[k][r0];
            const float4 b0 = *(const float4*)&bT[k][tn * 4];
            const float4 b1 = *(const float4*)&bT[k][64 + tn * 4];
            const float2 b2 = *(const float2*)&bT[k][128 + tn * 2];
            const float av[4]  = {a0.x,a0.y,a0.z,a0.w};
            const float bv[10] = {b0.x,b0.y,b0.z,b0.w,b1.x,b1.y,b1.z,b1.w,b2.x,b2.y};
            #pragma unroll
            for (int i = 0; i < 4; ++i)
                #pragma unroll
                for (int j = 0; j < 10; ++j)
                    acc[i][j] += av[i] * bv[j];
        }
    }
    #pragma unroll
    for (int i = 0; i < 4; ++i) {
        const size_t rowoff = (size_t)(m0 + r0 + i) * XDW;
        #pragma unroll
        for (int j = 0; j < 10; ++j) {
            const int col = (j < 4) ? (tn * 4 + j)
                          : (j < 8) ? (64 + tn * 4 + (j - 4))
                                    : (128 + tn * 2 + (j - 8));
            if (ATOMIC) atomicAdd(&out[rowoff + col], acc[i][j]);
            else        out[(size_t)blockIdx.y * XDBL_ELEMS + rowoff + col] = acc[i][j];
        }
    }
}

__global__ __launch_bounds__(256) void zero_xdbl(float4* p) {
    p[blockIdx.x * 256 + threadIdx.x] = make_float4(0.f, 0.f, 0.f, 0.f);  // 327680 float4s
}

__global__ __launch_bounds__(256) void reduce_part(const float* __restrict__ part,
                                                   float* __restrict__ xdbl) {
    const size_t i = (size_t)blockIdx.x * 256 + threadIdx.x;   // over 1,310,720
    float s = 0.f;
    #pragma unroll
    for (int k = 0; k < G1_KS; ++k) s += part[(size_t)k * XDBL_ELEMS + i];
    xdbl[i] = s;
}

// ================= GEMM2 + softplus =================
#define G2_BM 128
#define G2_BN 128
#define G2_BK 32
__global__ __launch_bounds__(256) void gemm2_delta(const float* __restrict__ xdbl,
                                                   const float* __restrict__ w2,
                                                   const float* __restrict__ bias,
                                                   float* __restrict__ dout) {
    __shared__ float xT[G2_BK][G2_BM + 4];
    __shared__ float wT[G2_BK][G2_BN + 4];
    const int m0 = blockIdx.x * G2_BM;
    const int n0 = blockIdx.y * G2_BN;
    const int tid = threadIdx.x;
    const int tm = tid >> 4, tn = tid & 15;
    const int r0 = tm * 8;
    const int sk = (tid & 7) * 4;
    const int sr = tid >> 3;

    float acc[8][8];
    #pragma unroll
    for (int i = 0; i < 8; ++i)
        #pragma unroll
        for (int j = 0; j < 8; ++j) acc[i][j] = 0.f;

    for (int ch = 0; ch < RNK / G2_BK; ++ch) {
        const int kc = ch * G2_BK;
        __syncthreads();
        #pragma unroll
        for (int p = 0; p < 4; ++p) {
            const int row = sr + p * 32;
            const float4 v = *(const float4*)(xdbl + (size_t)(m0 + row) * XDW + kc + sk);
            xT[sk + 0][row] = v.x; xT[sk + 1][row] = v.y;
            xT[sk + 2][row] = v.z; xT[sk + 3][row] = v.w;
        }
        #pragma unroll
        for (int p = 0; p < 4; ++p) {
            const int row = sr + p * 32;
            const float4 v = *(const float4*)(w2 + (size_t)(n0 + row) * RNK + kc + sk);
            wT[sk + 0][row] = v.x; wT[sk + 1][row] = v.y;
            wT[sk + 2][row] = v.z; wT[sk + 3][row] = v.w;
        }
        __syncthreads();
        #pragma unroll 4
        for (int k = 0; k < G2_BK; ++k) {
            const float4 a0 = *(const float4*)&xT[k][r0];
            const float4 a1 = *(const float4*)&xT[k][r0 + 4];
            const float4 b0 = *(const float4*)&wT[k][tn * 4];
            const float4 b1 = *(const float4*)&wT[k][64 + tn * 4];
            const float av[8] = {a0.x,a0.y,a0.z,a0.w,a1.x,a1.y,a1.z,a1.w};
            const float bv[8] = {b0.x,b0.y,b0.z,b0.w,b1.x,b1.y,b1.z,b1.w};
            #pragma unroll
            for (int i = 0; i < 8; ++i)
                #pragma unroll
                for (int j = 0; j < 8; ++j)
                    acc[i][j] += av[i] * bv[j];
        }
    }
    #pragma unroll
    for (int i = 0; i < 8; ++i) {
        float r[8];
        #pragma unroll
        for (int j = 0; j < 8; ++j) {
            const int col = (j < 4) ? (tn * 4 + j) : (64 + tn * 4 + (j - 4));
            const float x = acc[i][j] + bias[n0 + col];
            r[j] = (x > 20.f) ? x : log1pf(expf(x));
        }
        float* o = dout + (size_t)(m0 + r0 + i) * DM + n0;
        *(float4*)(o + tn * 4)      = make_float4(r[0], r[1], r[2], r[3]);
        *(float4*)(o + 64 + tn * 4) = make_float4(r[4], r[5], r[6], r[7]);
    }
}

// ================= Selective scan =================
// 16 lanes per (b,d); lane n owns h[n]. Depth-8 register prefetch.
// uint32 offsets from uniform bases -> s[base]+voffset addressing; per-batch
// pointer bumps (od += 8*DM, ob += 8*XDW) with compile-time per-j offsets;
// tail batch peeled so the main loop has NO clamp select.
// delta_in/y_out alias d_out: every same-address load/store pair is
// dataflow-dependent within its owning group, so restrict is sound.
__global__ __launch_bounds__(256) void scan_kernel(const float* __restrict__ hs,
                                                   const float* __restrict__ xdbl,
                                                   const float* __restrict__ Alog,
                                                   const float* __restrict__ Dvec,
                                                   const float* __restrict__ delta_in,
                                                   float* __restrict__ y_out) {
    const int b = blockIdx.y;
    const int g = threadIdx.x >> 4;
    const int n = threadIdx.x & 15;
    const int d = blockIdx.x * 16 + g;

    const float A  = -__expf(Alog[(size_t)d * DS + n]);
    const float Dd = Dvec[d];

    // uint32 element offsets (max ~16.7M, fits easily)
    unsigned od = (unsigned)(b * LSEQ) * DM + (unsigned)d;          // delta/u @ t
    unsigned ob = (unsigned)(b * LSEQ) * XDW + (unsigned)(RNK + n); // B @ t (C = +DS)

    float pd[8], pu[8], pB[8], pC[8];
    #pragma unroll
    for (int j = 0; j < 8; ++j) {
        pd[j] = delta_in[od + j * DM];
        pu[j] = hs[od + j * DM];
        pB[j] = xdbl[ob + j * XDW];
        pC[j] = xdbl[ob + j * XDW + DS];
    }

    float h = 0.f;
    for (int t0 = 0; t0 < LSEQ - 8; t0 += 8) {
        float pp[8], uD[8];
        #pragma unroll
        for (int j = 0; j < 8; ++j) {
            const float delta = pd[j];
            const float u     = pu[j];
            const float Bv    = pB[j];
            const float Cv    = pC[j];
            uD[j] = u * Dd;
            // unconditional prefetch of t0+8+j (max row index LSEQ-1 in last main batch)
            pd[j] = delta_in[od + (8 + j) * DM];
            pu[j] = hs[od + (8 + j) * DM];
            pB[j] = xdbl[ob + (8 + j) * XDW];
            pC[j] = xdbl[ob + (8 + j) * XDW + DS];

            h = __expf(delta * A) * h + (delta * u) * Bv;
            pp[j] = h * Cv;
        }
        #pragma unroll
        for (int s = 1; s < 16; s <<= 1)
            #pragma unroll
            for (int j = 0; j < 8; ++j)
                pp[j] += __shfl_xor(pp[j], s, 16);
        float v = pp[0] + uD[0];
        #pragma unroll
        for (int j = 1; j < 8; ++j) v = (n == j) ? (pp[j] + uD[j]) : v;
        if (n < 8) y_out[od + (unsigned)n * DM] = v;
        od += 8 * DM;
        ob += 8 * XDW;
    }
    // ---- peeled tail batch (t0 = LSEQ-8): no prefetch ----
    {
        float pp[8], uD[8];
        #pragma unroll
        for (int j = 0; j < 8; ++j) {
            const float delta = pd[j];
            const float u     = pu[j];
            uD[j] = u * Dd;
            h = __expf(delta * A) * h + (delta * u) * pB[j];
            pp[j] = h * pC[j];
        }
        #pragma unroll
        for (int s = 1; s < 16; s <<= 1)
            #pragma unroll
            for (int j = 0; j < 8; ++j)
                pp[j] += __shfl_xor(pp[j], s, 16);
        float v = pp[0] + uD[0];
        #pragma unroll
        for (int j = 1; j < 8; ++j) v = (n == j) ? (pp[j] + uD[j]) : v;
        if (n < 8) y_out[od + (unsigned)n * DM] = v;
    }
}

extern "C" void kernel_launch(void* const* d_in, const int* in_sizes, int n_in,
                              void* d_out, int out_size, void* d_ws, size_t ws_size,
                              hipStream_t stream) {
    const float* hs   = (const float*)d_in[0];
    const float* w1   = (const float*)d_in[1];
    const float* w2   = (const float*)d_in[2];
    const float* bias = (const float*)d_in[3];
    const float* Alog = (const float*)d_in[4];
    const float* Dvec = (const float*)d_in[5];
    float* dout = (float*)d_out;
    float* xdbl = (float*)d_ws;                          // 5.24 MB

    const size_t PART_OFF = (size_t)8 << 20;             // partials at ws+8MB
    const size_t need = PART_OFF + (size_t)G1_KS * XDBL_ELEMS * sizeof(float);

    if (ws_size >= need) {
        float* part = (float*)((char*)d_ws + PART_OFF);
        hipLaunchKernelGGL((gemm1_kern<false>), dim3(MTOT / G1_BM, G1_KS), dim3(256), 0, stream, hs, w1, part);
        hipLaunchKernelGGL(reduce_part, dim3((unsigned)(XDBL_ELEMS / 256)), dim3(256), 0, stream, part, xdbl);
    } else {
        hipLaunchKernelGGL(zero_xdbl, dim3((unsigned)(XDBL_ELEMS / 1024)), dim3(256), 0, stream, (float4*)xdbl);
        hipLaunchKernelGGL((gemm1_kern<true>), dim3(MTOT / G1_BM, G1_KS), dim3(256), 0, stream, hs, w1, xdbl);
    }
    hipLaunchKernelGGL(gemm2_delta, dim3(MTOT / G2_BM, DM / G2_BN), dim3(256), 0, stream, xdbl, w2, bias, dout);
    hipLaunchKernelGGL(scan_kernel, dim3(DM / 16, NB), dim3(256), 0, stream,
                       hs, xdbl, Alog, Dvec, dout, dout);
}

// Round 6
// 564.800 us; speedup vs baseline: 3.4110x; 1.0221x over previous
//
#include <hip/hip_runtime.h>
#include <hip/hip_bf16.h>
#include <math.h>

// MambaRecurrence: B=4, L=2048, D_MODEL=2048, D_STATE=16, DT_RANK=128
// Stage 1: x_dbl = hs @ x_proj_w^T  -> bf16 MFMA (16x16x32), K-split 8 + reduce
// Stage 2: delta = softplus(x_dbl[:, :128] @ dt_proj_w^T + b)  (fp32 LDS tile)
// Stage 3: scan — depth-8 prefetch, DPP (VALU-only) 16-lane reduction.

#define DM   2048
#define DS   16
#define RNK  128
#define XDW  160   // RNK + 2*DS
#define LSEQ 2048
#define NB   4
#define MTOT (NB * LSEQ)   // 8192

#define G1_BM   64
#define G1_BK   32
#define G1_KS   8                  // K-split factor
#define G1_KPB  (DM / G1_KS)       // 256 K per block
#define G1_NCH  (G1_KPB / G1_BK)
#define XDBL_ELEMS ((size_t)MTOT * XDW)

// ================= f32 -> bf16 conversion (exact-grid, 8 elems/thread) =====
typedef __attribute__((ext_vector_type(8))) unsigned short u16x8;
__global__ __launch_bounds__(256) void f32_to_bf16_kern(const float* __restrict__ in,
                                                        unsigned short* __restrict__ out) {
    const size_t i = ((size_t)blockIdx.x * 256 + threadIdx.x) * 8;
    const float4 v0 = *(const float4*)(in + i);
    const float4 v1 = *(const float4*)(in + i + 4);
    const float vv[8] = {v0.x, v0.y, v0.z, v0.w, v1.x, v1.y, v1.z, v1.w};
    u16x8 o;
    #pragma unroll
    for (int j = 0; j < 8; ++j) {
        __hip_bfloat16 h = __float2bfloat16(vv[j]);
        o[j] = *(unsigned short*)&h;
    }
    *(u16x8*)(out + i) = o;
}

// ================= GEMM1 (MFMA bf16): partials out[ks][8192][160] ==========
// Block 256 = 4 waves; wave w: rows m0+w*16 (16 rows) x all 160 cols.
// Frags per m89-verified layout: A lane=row(l&15), k=8*(l>>4)+j (contig 16B);
// B lane=col(l&15), same k (w1 row-major => contig 16B); D row=(l>>4)*4+r, col=l&15.
typedef __attribute__((ext_vector_type(8))) short bf16x8;
typedef __attribute__((ext_vector_type(4))) float f32x4;

__global__ __launch_bounds__(256) void gemm1_mfma(const unsigned short* __restrict__ hsb,
                                                  const unsigned short* __restrict__ w1b,
                                                  float* __restrict__ out) {
    const int w  = threadIdx.x >> 6;
    const int l  = threadIdx.x & 63;
    const int m0 = blockIdx.x * G1_BM + w * 16;
    const int k0 = blockIdx.y * G1_KPB;
    const int lr = l & 15;
    const int lk = (l >> 4) * 8;

    f32x4 acc[10];
    #pragma unroll
    for (int j = 0; j < 10; ++j) acc[j] = (f32x4){0.f, 0.f, 0.f, 0.f};

    const unsigned short* ap = hsb + (size_t)(m0 + lr) * DM + k0 + lk;
    const unsigned short* bp = w1b + (size_t)lr * DM + k0 + lk;
    for (int ks = 0; ks < G1_KPB / 32; ++ks) {          // 8 k-steps
        const bf16x8 a = *(const bf16x8*)(ap + ks * 32);
        #pragma unroll
        for (int j = 0; j < 10; ++j) {
            const bf16x8 b = *(const bf16x8*)(bp + (size_t)j * 16 * DM + ks * 32);
            acc[j] = __builtin_amdgcn_mfma_f32_16x16x32_bf16(a, b, acc[j], 0, 0, 0);
        }
    }
    float* op = out + (size_t)blockIdx.y * XDBL_ELEMS;
    #pragma unroll
    for (int j = 0; j < 10; ++j)
        #pragma unroll
        for (int r = 0; r < 4; ++r)
            op[(size_t)(m0 + (l >> 4) * 4 + r) * XDW + j * 16 + lr] = acc[j][r];
}

// ================= GEMM1 fp32 fallback (round-5 kernel) ====================
template<bool ATOMIC>
__global__ __launch_bounds__(256) void gemm1_kern(const float* __restrict__ hs,
                                                  const float* __restrict__ w1,
                                                  float* __restrict__ out) {
    __shared__ float aT[G1_BK][G1_BM + 4];
    __shared__ float bT[G1_BK][160 + 4];
    const int m0 = blockIdx.x * G1_BM;
    const int k0 = blockIdx.y * G1_KPB;
    const int tid = threadIdx.x;
    const int tm = tid >> 4, tn = tid & 15;
    const int r0 = tm * 4;
    const int sk = (tid & 7) * 4;
    const int sr = tid >> 3;

    float acc[4][10];
    #pragma unroll
    for (int i = 0; i < 4; ++i)
        #pragma unroll
        for (int j = 0; j < 10; ++j) acc[i][j] = 0.f;

    for (int ch = 0; ch < G1_NCH; ++ch) {
        const int kc = k0 + ch * G1_BK;
        __syncthreads();
        #pragma unroll
        for (int p = 0; p < 2; ++p) {
            const int row = sr + p * 32;
            const float4 v = *(const float4*)(hs + (size_t)(m0 + row) * DM + kc + sk);
            aT[sk + 0][row] = v.x; aT[sk + 1][row] = v.y;
            aT[sk + 2][row] = v.z; aT[sk + 3][row] = v.w;
        }
        #pragma unroll
        for (int p = 0; p < 5; ++p) {
            const int row = sr + p * 32;
            const float4 v = *(const float4*)(w1 + (size_t)row * DM + kc + sk);
            bT[sk + 0][row] = v.x; bT[sk + 1][row] = v.y;
            bT[sk + 2][row] = v.z; bT[sk + 3][row] = v.w;
        }
        __syncthreads();
        #pragma unroll 4
        for (int k = 0; k < G1_BK; ++k) {
            const float4 a0 = *(const float4*)&aT[k][r0];
            const float4 b0 = *(const float4*)&bT[k][tn * 4];
            const float4 b1 = *(const float4*)&bT[k][64 + tn * 4];
            const float2 b2 = *(const float2*)&bT[k][128 + tn * 2];
            const float av[4]  = {a0.x,a0.y,a0.z,a0.w};
            const float bv[10] = {b0.x,b0.y,b0.z,b0.w,b1.x,b1.y,b1.z,b1.w,b2.x,b2.y};
            #pragma unroll
            for (int i = 0; i < 4; ++i)
                #pragma unroll
                for (int j = 0; j < 10; ++j)
                    acc[i][j] += av[i] * bv[j];
        }
    }
    #pragma unroll
    for (int i = 0; i < 4; ++i) {
        const size_t rowoff = (size_t)(m0 + r0 + i) * XDW;
        #pragma unroll
        for (int j = 0; j < 10; ++j) {
            const int col = (j < 4) ? (tn * 4 + j)
                          : (j < 8) ? (64 + tn * 4 + (j - 4))
                                    : (128 + tn * 2 + (j - 8));
            if (ATOMIC) atomicAdd(&out[rowoff + col], acc[i][j]);
            else        out[(size_t)blockIdx.y * XDBL_ELEMS + rowoff + col] = acc[i][j];
        }
    }
}

__global__ __launch_bounds__(256) void zero_xdbl(float4* p) {
    p[blockIdx.x * 256 + threadIdx.x] = make_float4(0.f, 0.f, 0.f, 0.f);
}

__global__ __launch_bounds__(256) void reduce_part(const float* __restrict__ part,
                                                   float* __restrict__ xdbl) {
    const size_t i = (size_t)blockIdx.x * 256 + threadIdx.x;
    float s = 0.f;
    #pragma unroll
    for (int k = 0; k < G1_KS; ++k) s += part[(size_t)k * XDBL_ELEMS + i];
    xdbl[i] = s;
}

// ================= GEMM2 + softplus =================
#define G2_BM 128
#define G2_BN 128
#define G2_BK 32
__global__ __launch_bounds__(256) void gemm2_delta(const float* __restrict__ xdbl,
                                                   const float* __restrict__ w2,
                                                   const float* __restrict__ bias,
                                                   float* __restrict__ dout) {
    __shared__ float xT[G2_BK][G2_BM + 4];
    __shared__ float wT[G2_BK][G2_BN + 4];
    const int m0 = blockIdx.x * G2_BM;
    const int n0 = blockIdx.y * G2_BN;
    const int tid = threadIdx.x;
    const int tm = tid >> 4, tn = tid & 15;
    const int r0 = tm * 8;
    const int sk = (tid & 7) * 4;
    const int sr = tid >> 3;

    float acc[8][8];
    #pragma unroll
    for (int i = 0; i < 8; ++i)
        #pragma unroll
        for (int j = 0; j < 8; ++j) acc[i][j] = 0.f;

    for (int ch = 0; ch < RNK / G2_BK; ++ch) {
        const int kc = ch * G2_BK;
        __syncthreads();
        #pragma unroll
        for (int p = 0; p < 4; ++p) {
            const int row = sr + p * 32;
            const float4 v = *(const float4*)(xdbl + (size_t)(m0 + row) * XDW + kc + sk);
            xT[sk + 0][row] = v.x; xT[sk + 1][row] = v.y;
            xT[sk + 2][row] = v.z; xT[sk + 3][row] = v.w;
        }
        #pragma unroll
        for (int p = 0; p < 4; ++p) {
            const int row = sr + p * 32;
            const float4 v = *(const float4*)(w2 + (size_t)(n0 + row) * RNK + kc + sk);
            wT[sk + 0][row] = v.x; wT[sk + 1][row] = v.y;
            wT[sk + 2][row] = v.z; wT[sk + 3][row] = v.w;
        }
        __syncthreads();
        #pragma unroll 4
        for (int k = 0; k < G2_BK; ++k) {
            const float4 a0 = *(const float4*)&xT[k][r0];
            const float4 a1 = *(const float4*)&xT[k][r0 + 4];
            const float4 b0 = *(const float4*)&wT[k][tn * 4];
            const float4 b1 = *(const float4*)&wT[k][64 + tn * 4];
            const float av[8] = {a0.x,a0.y,a0.z,a0.w,a1.x,a1.y,a1.z,a1.w};
            const float bv[8] = {b0.x,b0.y,b0.z,b0.w,b1.x,b1.y,b1.z,b1.w};
            #pragma unroll
            for (int i = 0; i < 8; ++i)
                #pragma unroll
                for (int j = 0; j < 8; ++j)
                    acc[i][j] += av[i] * bv[j];
        }
    }
    #pragma unroll
    for (int i = 0; i < 8; ++i) {
        float r[8];
        #pragma unroll
        for (int j = 0; j < 8; ++j) {
            const int col = (j < 4) ? (tn * 4 + j) : (64 + tn * 4 + (j - 4));
            const float x = acc[i][j] + bias[n0 + col];
            r[j] = (x > 20.f) ? x : log1pf(expf(x));
        }
        float* o = dout + (size_t)(m0 + r0 + i) * DM + n0;
        *(float4*)(o + tn * 4)      = make_float4(r[0], r[1], r[2], r[3]);
        *(float4*)(o + 64 + tn * 4) = make_float4(r[4], r[5], r[6], r[7]);
    }
}

// ================= Selective scan =================
// DPP-based 16-lane sum: quad_perm xor1, xor2, then row_ror:4, row_ror:8.
// All VALU (fused v_add_f32 dpp), no LDS pipe, no lgkm waits.
template<int CTRL>
__device__ __forceinline__ float dpp_addstep(float x) {
    const int yi = __builtin_amdgcn_update_dpp(0, __builtin_bit_cast(int, x),
                                               CTRL, 0xF, 0xF, true);
    return x + __builtin_bit_cast(float, yi);
}
__device__ __forceinline__ float red16(float x) {
    x = dpp_addstep<0xB1>(x);    // quad_perm [1,0,3,2]  (xor 1)
    x = dpp_addstep<0x4E>(x);    // quad_perm [2,3,0,1]  (xor 2)
    x = dpp_addstep<0x124>(x);   // row_ror:4
    x = dpp_addstep<0x128>(x);   // row_ror:8 -> full 16-lane sum, all lanes
    return x;
}

__global__ __launch_bounds__(256) void scan_kernel(const float* __restrict__ hs,
                                                   const float* __restrict__ xdbl,
                                                   const float* __restrict__ Alog,
                                                   const float* __restrict__ Dvec,
                                                   const float* __restrict__ delta_in,
                                                   float* __restrict__ y_out) {
    const int b = blockIdx.y;
    const int g = threadIdx.x >> 4;
    const int n = threadIdx.x & 15;
    const int d = blockIdx.x * 16 + g;

    const float A  = -__expf(Alog[(size_t)d * DS + n]);
    const float Dd = Dvec[d];

    unsigned od = (unsigned)(b * LSEQ) * DM + (unsigned)d;
    unsigned ob = (unsigned)(b * LSEQ) * XDW + (unsigned)(RNK + n);

    float pd[8], pu[8], pB[8], pC[8];
    #pragma unroll
    for (int j = 0; j < 8; ++j) {
        pd[j] = delta_in[od + j * DM];
        pu[j] = hs[od + j * DM];
        pB[j] = xdbl[ob + j * XDW];
        pC[j] = xdbl[ob + j * XDW + DS];
    }

    float h = 0.f;
    for (int t0 = 0; t0 < LSEQ - 8; t0 += 8) {
        float pp[8], uD[8];
        #pragma unroll
        for (int j = 0; j < 8; ++j) {
            const float delta = pd[j];
            const float u     = pu[j];
            const float Bv    = pB[j];
            const float Cv    = pC[j];
            uD[j] = u * Dd;
            pd[j] = delta_in[od + (8 + j) * DM];
            pu[j] = hs[od + (8 + j) * DM];
            pB[j] = xdbl[ob + (8 + j) * XDW];
            pC[j] = xdbl[ob + (8 + j) * XDW + DS];

            h = __expf(delta * A) * h + (delta * u) * Bv;
            pp[j] = h * Cv;
        }
        #pragma unroll
        for (int j = 0; j < 8; ++j) pp[j] = red16(pp[j]);
        float v = pp[0] + uD[0];
        #pragma unroll
        for (int j = 1; j < 8; ++j) v = (n == j) ? (pp[j] + uD[j]) : v;
        if (n < 8) y_out[od + (unsigned)n * DM] = v;
        od += 8 * DM;
        ob += 8 * XDW;
    }
    {   // peeled tail (t0 = LSEQ-8): no prefetch
        float pp[8], uD[8];
        #pragma unroll
        for (int j = 0; j < 8; ++j) {
            const float delta = pd[j];
            const float u     = pu[j];
            uD[j] = u * Dd;
            h = __expf(delta * A) * h + (delta * u) * pB[j];
            pp[j] = h * pC[j];
        }
        #pragma unroll
        for (int j = 0; j < 8; ++j) pp[j] = red16(pp[j]);
        float v = pp[0] + uD[0];
        #pragma unroll
        for (int j = 1; j < 8; ++j) v = (n == j) ? (pp[j] + uD[j]) : v;
        if (n < 8) y_out[od + (unsigned)n * DM] = v;
    }
}

extern "C" void kernel_launch(void* const* d_in, const int* in_sizes, int n_in,
                              void* d_out, int out_size, void* d_ws, size_t ws_size,
                              hipStream_t stream) {
    const float* hs   = (const float*)d_in[0];
    const float* w1   = (const float*)d_in[1];
    const float* w2   = (const float*)d_in[2];
    const float* bias = (const float*)d_in[3];
    const float* Alog = (const float*)d_in[4];
    const float* Dvec = (const float*)d_in[5];
    float* dout = (float*)d_out;
    float* xdbl = (float*)d_ws;                                  // 5.24 MB

    const size_t OFF_PART  = (size_t)8 << 20;                    // partials @ 8MB
    const size_t PART_B    = (size_t)G1_KS * XDBL_ELEMS * 4;     // 41.9MB
    const size_t OFF_HSB   = (OFF_PART + PART_B + 255) & ~(size_t)255;
    const size_t HSB_B     = (size_t)MTOT * DM * 2;              // 32MB
    const size_t OFF_W1B   = OFF_HSB + HSB_B;
    const size_t W1B_B     = (size_t)XDW * DM * 2;               // 640KB
    const size_t need_mfma = OFF_W1B + W1B_B;
    const size_t need_part = OFF_PART + PART_B;

    if (ws_size >= need_mfma) {
        unsigned short* hsb = (unsigned short*)((char*)d_ws + OFF_HSB);
        unsigned short* w1b = (unsigned short*)((char*)d_ws + OFF_W1B);
        float* part = (float*)((char*)d_ws + OFF_PART);
        hipLaunchKernelGGL(f32_to_bf16_kern, dim3(MTOT * DM / 8 / 256), dim3(256), 0, stream, hs, hsb);
        hipLaunchKernelGGL(f32_to_bf16_kern, dim3(XDW * DM / 8 / 256),  dim3(256), 0, stream, w1, w1b);
        hipLaunchKernelGGL(gemm1_mfma, dim3(MTOT / G1_BM, G1_KS), dim3(256), 0, stream, hsb, w1b, part);
        hipLaunchKernelGGL(reduce_part, dim3((unsigned)(XDBL_ELEMS / 256)), dim3(256), 0, stream, part, xdbl);
    } else if (ws_size >= need_part) {
        float* part = (float*)((char*)d_ws + OFF_PART);
        hipLaunchKernelGGL((gemm1_kern<false>), dim3(MTOT / G1_BM, G1_KS), dim3(256), 0, stream, hs, w1, part);
        hipLaunchKernelGGL(reduce_part, dim3((unsigned)(XDBL_ELEMS / 256)), dim3(256), 0, stream, part, xdbl);
    } else {
        hipLaunchKernelGGL(zero_xdbl, dim3((unsigned)(XDBL_ELEMS / 1024)), dim3(256), 0, stream, (float4*)xdbl);
        hipLaunchKernelGGL((gemm1_kern<true>), dim3(MTOT / G1_BM, G1_KS), dim3(256), 0, stream, hs, w1, xdbl);
    }
    hipLaunchKernelGGL(gemm2_delta, dim3(MTOT / G2_BM, DM / G2_BN), dim3(256), 0, stream, xdbl, w2, bias, dout);
    hipLaunchKernelGGL(scan_kernel, dim3(DM / 16, NB), dim3(256), 0, stream,
                       hs, xdbl, Alog, Dvec, dout, dout);
}